// Round 8
// baseline (1526.475 us; speedup 1.0000x reference)
//
#include <hip/hip_runtime.h>
#include <stdint.h>

typedef __bf16 bf16x8 __attribute__((ext_vector_type(8)));
typedef float f32x4 __attribute__((ext_vector_type(4)));
typedef unsigned short ushort8 __attribute__((ext_vector_type(8)));

#define DEV static __device__ __forceinline__

DEV float bf2f(unsigned short h) {
  union { unsigned u; float f; } v; v.u = ((unsigned)h) << 16; return v.f;
}
DEV unsigned short f2bf(float f) {
  union { float f; unsigned u; } v; v.f = f;
  unsigned r = v.u + 0x7fffu + ((v.u >> 16) & 1u);  // RNE
  return (unsigned short)(r >> 16);
}
DEV float gelu_f(float x) {  // jax.nn.gelu approximate=True (tanh)
  const float c = 0.7978845608028654f;
  return 0.5f * x * (1.f + tanhf(c * (x + 0.044715f * x * x * x)));
}

// par = which z_s buffer (0/1) holds the current solver state.
struct Scalars { int active; int step_active; int steps; float t; float dt; int par; };

// idx width probe (int64 -> (id,0,id,0,...) viewed as int32). Proven harmless.
__global__ void detect_idx_kernel(const int* idx, int* i64f) {
  __shared__ int anyOdd, anyEven;
  if (threadIdx.x == 0) { anyOdd = 0; anyEven = 0; }
  __syncthreads();
  for (int j = threadIdx.x; j < 1024; j += 256) {
    int v = idx[j];
    if (j & 1) { if (v != 0) anyOdd = 1; }
    else       { if (v != 0) anyEven = 1; }
  }
  __syncthreads();
  if (threadIdx.x == 0) *i64f = (anyOdd == 0 && anyEven == 1) ? 1 : 0;
}

__global__ void sentinel_kernel(float* out, float val) {
  if (val != 0.f) out[0] = val;
}

// ---------------------------------------------------------------------------
// Transpose-convert: src f32, tile [ty*64..][tx*64..] of [R][C] row-major
// -> dst bf16 [n=tx*64+..][kOff + ty*64+..], optional per-k scale g[k].
// ---------------------------------------------------------------------------
DEV void tr_tile2(const float* src, int ldS, unsigned short* dst, int ldD,
                  int kOff, int tx, int ty, const float* gsc, float (*lds)[65]) {
  const int tid = threadIdx.x;
#pragma unroll
  for (int jj = 0; jj < 4; ++jj) {
    int r = jj * 16 + (tid >> 4);
    int c = (tid & 15) * 4;
    float4 v = *(const float4*)&src[(size_t)(ty * 64 + r) * ldS + tx * 64 + c];
    lds[r][c] = v.x; lds[r][c + 1] = v.y; lds[r][c + 2] = v.z; lds[r][c + 3] = v.w;
  }
  __syncthreads();
  const int lr = tid >> 2, seg = (tid & 3) * 16;
  ushort8 o0, o1;
#pragma unroll
  for (int e = 0; e < 8; ++e) {
    float gs = gsc ? gsc[ty * 64 + seg + e] : 1.f;
    o0[e] = f2bf(lds[seg + e][lr] * gs);
  }
#pragma unroll
  for (int e = 0; e < 8; ++e) {
    float gs = gsc ? gsc[ty * 64 + seg + 8 + e] : 1.f;
    o1[e] = f2bf(lds[seg + 8 + e][lr] * gs);
  }
  unsigned short* dp = dst + (size_t)(tx * 64 + lr) * ldD + kOff + ty * 64 + seg;
  *(ushort8*)dp = o0;
  *(ushort8*)(dp + 8) = o1;
}

// ---------------------------------------------------------------------------
// combine: z_prev += current solver state (masked by exited), applying the
// pending Euler update (sc->step_active/dt on z_s[sc->par]); writes next-layer
// state into z_s0 (par resets to 0) and optional exit-head LN -> zn.
// ---------------------------------------------------------------------------
DEV void combine_body(int cb, int tid, float* z_prev, float* z_s0, float* z_s1,
                      const float* dz, const int* exited, const Scalars* sc,
                      const float* eg, const float* eb, int goff,
                      unsigned short* zn, int doLN) {
  const int wave = tid >> 6, lane = tid & 63;
  const int sa = sc->step_active;
  const float dt = sc->dt;
  const float* zin = sc->par ? z_s1 : z_s0;
  int tok = cb * 4 + wave;
  int ex = exited[tok];
  float a[4];
#pragma unroll
  for (int j = 0; j < 4; ++j) {
    int d = lane + 64 * j;
    float bb = zin[(size_t)tok * 256 + d];
    if (sa) bb += dt * dz[(size_t)tok * 256 + d];
    float ap = z_prev[(size_t)tok * 256 + d];
    float an = ex ? ap : (ap + bb);
    a[j] = an;
    if (!ex) z_prev[(size_t)tok * 256 + d] = an;
    z_s0[(size_t)tok * 256 + d] = an;
  }
  if (!doLN) return;
  float ss = 0.f, s2 = 0.f;
#pragma unroll
  for (int j = 0; j < 4; ++j) { ss += a[j]; s2 += a[j] * a[j]; }
#pragma unroll
  for (int o = 1; o < 64; o <<= 1) {
    ss += __shfl_xor(ss, o); s2 += __shfl_xor(s2, o);
  }
  float mean = ss * (1.f / 256.f);
  float var = s2 * (1.f / 256.f) - mean * mean;
  float rstd = rsqrtf(var + 1e-5f);
#pragma unroll
  for (int j = 0; j < 4; ++j) {
    int d = lane + 64 * j;
    zn[(size_t)tok * 256 + d] =
        f2bf((a[j] - mean) * rstd * eg[goff + d] + eb[goff + d]);
  }
}

// Per-layer weight prep; for i>=1 grid=455 and blocks 199..454 run the fused
// combine of the PREVIOUS layer (reads scPrev slot; block 0 inits scInit slot
// -- different slots, no race).
__global__ __launch_bounds__(256) void tr_weights_kernel(
    const float* wqkv, const float* wo, const float* w1, const float* w2,
    const float* g1, const float* b1ln, const float* g2, const float* b2ln,
    const float* b1mlp, unsigned short* bcat, unsigned short* wcat,
    float* biasf, Scalars* scInit,
    const Scalars* scPrev, float* z_prev, float* z_s0, float* z_s1,
    const float* dz, const int* exited,
    const float* eg, const float* eb, int goff, unsigned short* zn, int doLN) {
  int t = blockIdx.x;
  if (t == 0 && threadIdx.x == 0) {
    scInit->active = 1; scInit->step_active = 0; scInit->steps = 0;
    scInit->t = 0.f; scInit->dt = 0.f; scInit->par = 0;
  }
  if (t >= 199) {  // fused combine for previous layer
    combine_body(t - 199, threadIdx.x, z_prev, z_s0, z_s1, dz, exited, scPrev,
                 eg, eb, goff, zn, doLN);
    return;
  }
  if (t >= 192) {
    int n = (t - 192) * 256 + threadIdx.x;  // 0..1791 folded bias
    float acc = 0.f;
    if (n < 768) {
      for (int k = 0; k < 256; ++k) acc += b1ln[k] * wqkv[(size_t)k * 768 + n];
    } else {
      int mc = n - 768;
      acc = b1mlp[mc];
      for (int k = 0; k < 256; ++k) acc += b2ln[k] * w1[(size_t)k * 1024 + mc];
    }
    biasf[n] = acc;
    return;
  }
  __shared__ float lds[64][65];
  if (t < 48) {
    tr_tile2(wqkv, 768, bcat, 256, 0, t % 12, t / 12, g1, lds);
  } else if (t < 112) {
    int u = t - 48;
    tr_tile2(w1, 1024, bcat + 768 * 256, 256, 0, u % 16, u / 16, g2, lds);
  } else if (t < 128) {
    int u = t - 112;
    tr_tile2(wo, 256, wcat, 1280, 0, u % 4, u / 4, nullptr, lds);
  } else {
    int u = t - 128;
    tr_tile2(w2, 256, wcat, 1280, 256, u % 4, u / 4, nullptr, lds);
  }
}

// Standalone combine for the last layer.
__global__ __launch_bounds__(256) void combine_kernel(
    float* z_prev, float* z_s0, float* z_s1, const float* dz,
    const int* exited, const Scalars* sc, const float* eg, const float* eb,
    int goff, unsigned short* zn, int doLN) {
  combine_body(blockIdx.x, threadIdx.x, z_prev, z_s0, z_s1, dz, exited, sc,
               eg, eb, goff, zn, doLN);
}

// ehead[i] f32 [256][16384] -> bheadT bf16 [16384][256] (into Sbuf).
__global__ __launch_bounds__(256) void tr_mat_kernel(const float* src,
                                                     unsigned short* dst) {
  __shared__ float lds[64][65];
  tr_tile2(src, 16384, dst, 256, 0, blockIdx.x, blockIdx.y, nullptr, lds);
}

// ---------------------------------------------------------------------------
// 64x64 MFMA GEMM core: acc += A[64 rows x K] * B[64 rows x K]^T (B as [N,K]).
// ---------------------------------------------------------------------------
DEV void gemm64(const unsigned short* Ap, int lda, const unsigned short* Bp,
                int ldb, int K, unsigned short (*As)[40], unsigned short (*Bs)[40],
                int tid, f32x4 (&acc)[2][2]) {
  const int lane = tid & 63, wave = tid >> 6;
  const int quad = lane >> 4, l16 = lane & 15;
  const int wr = (wave >> 1) * 32, wc = (wave & 1) * 32;
  const int rowA = tid >> 2, segA = (tid & 3) * 8;
  for (int k0 = 0; k0 < K; k0 += 32) {
    *(ushort8*)&As[rowA][segA] =
        *(const ushort8*)(Ap + (size_t)rowA * lda + k0 + segA);
    *(ushort8*)&Bs[rowA][segA] =
        *(const ushort8*)(Bp + (size_t)rowA * ldb + k0 + segA);
    __syncthreads();
    bf16x8 a0 = *(const bf16x8*)&As[wr + l16][quad * 8];
    bf16x8 a1 = *(const bf16x8*)&As[wr + 16 + l16][quad * 8];
    bf16x8 b0 = *(const bf16x8*)&Bs[wc + l16][quad * 8];
    bf16x8 b1 = *(const bf16x8*)&Bs[wc + 16 + l16][quad * 8];
    acc[0][0] = __builtin_amdgcn_mfma_f32_16x16x32_bf16(a0, b0, acc[0][0], 0, 0, 0);
    acc[0][1] = __builtin_amdgcn_mfma_f32_16x16x32_bf16(a0, b1, acc[0][1], 0, 0, 0);
    acc[1][0] = __builtin_amdgcn_mfma_f32_16x16x32_bf16(a1, b0, acc[1][0], 0, 0, 0);
    acc[1][1] = __builtin_amdgcn_mfma_f32_16x16x32_bf16(a1, b1, acc[1][1], 0, 0, 0);
    __syncthreads();
  }
}

// ---------------------------------------------------------------------------
// FUSED1': scalar read + pending Euler update (z_s parity dbuf; only by==0
// writes) + per-row LN (stats prepass, normalize during A-staging) +
// [qkv | gelu-mlp-mid] = LN(z) @ bcat^T. Grid (16, 28).
// ---------------------------------------------------------------------------
__global__ __launch_bounds__(256) void gemm_fused1(
    float* z_s0, float* z_s1, const float* dz,
    const unsigned short* bcat, const float* biasf,
    unsigned short* qkvb, unsigned short* VT, unsigned short* af,
    const Scalars* sc) {
  if (!sc->active) return;
  const int sa = sc->step_active;
  const float dt = sc->dt;
  const float* zin = sc->par ? z_s1 : z_s0;
  float* zout = sc->par ? z_s0 : z_s1;

  const int bm = blockIdx.x * 64, bn = blockIdx.y * 64;
  const int tid = threadIdx.x;
  const int lane = tid & 63, wave = tid >> 6;
  const int quad = lane >> 4, l16 = lane & 15;
  const int wr = (wave >> 1) * 32, wc = (wave & 1) * 32;

  __shared__ __align__(16) unsigned short As[64][40];
  __shared__ __align__(16) unsigned short Bs[64][40];
  __shared__ float mrs[64][2];

  // ---- stats prepass (+ Euler update write by bn-group 0) ----
  {
    const int r = tid >> 2, cs = (tid & 3) * 64;
    const float4* zp = (const float4*)(zin + (size_t)(bm + r) * 256 + cs);
    const float4* dp = (const float4*)(dz + (size_t)(bm + r) * 256 + cs);
    float4* op = (float4*)(zout + (size_t)(bm + r) * 256 + cs);
    const bool wr0 = (blockIdx.y == 0);
    float sum = 0.f, ss = 0.f;
#pragma unroll
    for (int j = 0; j < 16; ++j) {
      float4 a = zp[j];
      if (sa) {
        float4 d = dp[j];
        a.x += dt * d.x; a.y += dt * d.y; a.z += dt * d.z; a.w += dt * d.w;
        if (wr0) op[j] = a;
      }
      sum += (a.x + a.y) + (a.z + a.w);
      ss += (a.x * a.x + a.y * a.y) + (a.z * a.z + a.w * a.w);
    }
    sum += __shfl_xor(sum, 1); ss += __shfl_xor(ss, 1);
    sum += __shfl_xor(sum, 2); ss += __shfl_xor(ss, 2);
    float mean = sum * (1.f / 256.f);
    float var = ss * (1.f / 256.f) - mean * mean;
    float rstd = rsqrtf(var + 1e-5f);
    if ((tid & 3) == 0) { mrs[r][0] = mean; mrs[r][1] = rstd; }
  }
  __syncthreads();

  const int rowA = tid >> 2, segA = (tid & 3) * 8;
  const float rmean = mrs[rowA][0], rrstd = mrs[rowA][1];
  f32x4 acc[2][2] = {};

  for (int k0 = 0; k0 < 256; k0 += 32) {
    // A: load z f32 (+dt*dz), normalize, convert
    const float4* zp = (const float4*)(zin + (size_t)(bm + rowA) * 256 + k0 + segA);
    float4 a0 = zp[0], a1 = zp[1];
    if (sa) {
      const float4* dp = (const float4*)(dz + (size_t)(bm + rowA) * 256 + k0 + segA);
      float4 d0 = dp[0], d1 = dp[1];
      a0.x += dt * d0.x; a0.y += dt * d0.y; a0.z += dt * d0.z; a0.w += dt * d0.w;
      a1.x += dt * d1.x; a1.y += dt * d1.y; a1.z += dt * d1.z; a1.w += dt * d1.w;
    }
    ushort8 av;
    av[0] = f2bf((a0.x - rmean) * rrstd); av[1] = f2bf((a0.y - rmean) * rrstd);
    av[2] = f2bf((a0.z - rmean) * rrstd); av[3] = f2bf((a0.w - rmean) * rrstd);
    av[4] = f2bf((a1.x - rmean) * rrstd); av[5] = f2bf((a1.y - rmean) * rrstd);
    av[6] = f2bf((a1.z - rmean) * rrstd); av[7] = f2bf((a1.w - rmean) * rrstd);
    *(ushort8*)&As[rowA][segA] = av;
    *(ushort8*)&Bs[rowA][segA] =
        *(const ushort8*)(bcat + (size_t)(bn + rowA) * 256 + k0 + segA);
    __syncthreads();

    bf16x8 fa0 = *(const bf16x8*)&As[wr + l16][quad * 8];
    bf16x8 fa1 = *(const bf16x8*)&As[wr + 16 + l16][quad * 8];
    bf16x8 fb0 = *(const bf16x8*)&Bs[wc + l16][quad * 8];
    bf16x8 fb1 = *(const bf16x8*)&Bs[wc + 16 + l16][quad * 8];
    acc[0][0] = __builtin_amdgcn_mfma_f32_16x16x32_bf16(fa0, fb0, acc[0][0], 0, 0, 0);
    acc[0][1] = __builtin_amdgcn_mfma_f32_16x16x32_bf16(fa0, fb1, acc[0][1], 0, 0, 0);
    acc[1][0] = __builtin_amdgcn_mfma_f32_16x16x32_bf16(fa1, fb0, acc[1][0], 0, 0, 0);
    acc[1][1] = __builtin_amdgcn_mfma_f32_16x16x32_bf16(fa1, fb1, acc[1][1], 0, 0, 0);
    __syncthreads();
  }

#pragma unroll
  for (int i2 = 0; i2 < 2; ++i2)
#pragma unroll
    for (int j = 0; j < 2; ++j)
#pragma unroll
      for (int r = 0; r < 4; ++r) {
        int row = bm + wr + i2 * 16 + quad * 4 + r;
        int col = bn + wc + j * 16 + l16;
        float val = acc[i2][j][r] + biasf[col];
        if (col < 768) {  // qkv (block-uniform: tile 64 | 768)
          unsigned short bv = f2bf(val);
          qkvb[(size_t)row * 768 + col] = bv;
          if (col >= 512) {  // V transposed: VT[h][hd][tok]
            int cc = col - 512;
            VT[((cc >> 6) << 16) + ((cc & 63) << 10) + row] = bv;
          }
        } else {  // mlp mid: gelu -> af cols 256..1279
          af[(size_t)row * 1280 + 256 + (col - 768)] = f2bf(gelu_f(val));
        }
      }
}

// ---------------------------------------------------------------------------
// ADD2: dz = [O|hmid] @ wcat^T + b2, per-row normsq atomics; the LAST
// finishing block (fence + counter -- no co-residency assumption) reduces
// nsq, computes the ODE scalar transition, updates sc (incl. par flip),
// zeroes nsq and the counter for the next step. Grid (16, 4).
// ---------------------------------------------------------------------------
__global__ __launch_bounds__(256) void gemm_add2(
    const unsigned short* af, const unsigned short* wcat, float* dzout,
    const float* b2, float* nsq, int* counter, Scalars* sc) {
  if (!sc->active) return;
  const int bm = blockIdx.x * 64, bn = blockIdx.y * 64;
  const int tid = threadIdx.x;
  const int lane = tid & 63, wave = tid >> 6;
  const int quad = lane >> 4, l16 = lane & 15;
  const int wr = (wave >> 1) * 32, wc = (wave & 1) * 32;
  __shared__ __align__(16) unsigned short As[64][40];
  __shared__ __align__(16) unsigned short Bs[64][40];
  f32x4 acc[2][2] = {};
  gemm64(af + (size_t)bm * 1280, 1280, wcat + (size_t)bn * 1280, 1280, 1280,
         As, Bs, tid, acc);
#pragma unroll
  for (int i2 = 0; i2 < 2; ++i2)
#pragma unroll
    for (int r = 0; r < 4; ++r) {
      int row = bm + wr + i2 * 16 + quad * 4 + r;
      float sq = 0.f;
#pragma unroll
      for (int j = 0; j < 2; ++j) {
        int col = bn + wc + j * 16 + l16;
        float val = acc[i2][j][r] + b2[col];
        dzout[(size_t)row * 256 + col] = val;
        sq += val * val;
      }
      sq += __shfl_xor(sq, 1); sq += __shfl_xor(sq, 2);
      sq += __shfl_xor(sq, 4); sq += __shfl_xor(sq, 8);
      if (l16 == 0) atomicAdd(nsq + row, sq);
    }
  __threadfence();
  __syncthreads();
  __shared__ int lastFlag;
  if (tid == 0) lastFlag = (atomicAdd(counter, 1) == 63) ? 1 : 0;
  __syncthreads();
  if (!lastFlag) return;
  // last block: scalar transition (identical tree to round 6)
  __shared__ float red[256];
  float v = (sqrtf(nsq[tid]) + sqrtf(nsq[tid + 512])) +
            (sqrtf(nsq[tid + 256]) + sqrtf(nsq[tid + 768]));
  red[tid] = v;
  __syncthreads();
  for (int o = 128; o; o >>= 1) {
    if (tid < o) red[tid] += red[tid + o];
    __syncthreads();
  }
  if (tid == 0) {
    Scalars st = *sc;
    int npar = st.step_active ? (st.par ^ 1) : st.par;  // did FUSED1' flip z?
    float mc = red[0] * (1.f / 1024.f);
    float scale = fminf(fmaxf(1.f / (1.f + mc), 0.5f), 2.f);
    float ddt = fminf(0.5f * scale, 1.f - st.t);  // dt_base = 1/MIN_STEPS
    st.dt = ddt; st.step_active = 1;
    st.t += ddt; st.steps += 1;
    int conv = (ddt * mc < 0.1f) && (st.steps >= 2);
    st.active = ((st.t < 1.f - 1e-6f) && !conv) ? 1 : 0;
    st.par = npar;
    *sc = st;
    *counter = 0;
  }
  nsq[tid] = 0.f; nsq[tid + 256] = 0.f; nsq[tid + 512] = 0.f; nsq[tid + 768] = 0.f;
}

// ---------------------------------------------------------------------------
// Fused attention (verbatim round 6): one block per (16-row Q-tile, head).
// ---------------------------------------------------------------------------
__global__ __launch_bounds__(256) void attn_kernel(
    const unsigned short* qkvb, const unsigned short* VT,
    unsigned short* af, const int* guard) {
  if (*guard == 0) return;
  const int qt = blockIdx.x;          // 16-row tile, 0..63
  const int h = blockIdx.y;
  const int nkt = (qt >> 2) + 1;      // causal 64-col band count
  __shared__ __align__(16) unsigned short S[16][1064];
  __shared__ __align__(16) unsigned short KV[64][88];
  const int tid = threadIdx.x, lane = tid & 63, wave = tid >> 6;
  const int quad = lane >> 4, l16 = lane & 15;
  const int srow = tid >> 3, scol = (tid & 7) * 8;

  bf16x8 aq[2];
  {
    const unsigned short* Qp =
        qkvb + (size_t)(qt * 16 + l16) * 768 + h * 64 + quad * 8;
    aq[0] = *(const bf16x8*)Qp;
    aq[1] = *(const bf16x8*)(Qp + 32);
  }

  for (int kt = 0; kt < nkt; ++kt) {
    const unsigned short* Kp = qkvb + (size_t)(kt * 64) * 768 + 256 + h * 64;
#pragma unroll
    for (int hh = 0; hh < 2; ++hh)
      *(ushort8*)&KV[hh * 32 + srow][scol] =
          *(const ushort8*)(Kp + (size_t)(hh * 32 + srow) * 768 + scol);
    __syncthreads();
    f32x4 sa2 = {};
#pragma unroll
    for (int k0 = 0; k0 < 2; ++k0) {
      bf16x8 bb = *(const bf16x8*)&KV[wave * 16 + l16][k0 * 32 + quad * 8];
      sa2 = __builtin_amdgcn_mfma_f32_16x16x32_bf16(aq[k0], bb, sa2, 0, 0, 0);
    }
#pragma unroll
    for (int r = 0; r < 4; ++r) {
      int rowg = qt * 16 + quad * 4 + r;
      int colg = kt * 64 + wave * 16 + l16;
      float o = (colg <= rowg) ? sa2[r] * 0.125f : -1e9f;
      S[quad * 4 + r][kt * 64 + wave * 16 + l16] = f2bf(o);
    }
    __syncthreads();
  }

  const int rowEnd = nkt * 64;
#pragma unroll
  for (int it = 0; it < 4; ++it) {
    int r = it * 4 + wave;
    unsigned short* p = &S[r][0];
    float v[16];
    float m = -1e30f;
#pragma unroll
    for (int ps = 0; ps < 4; ++ps) {
      int c = ps * 256 + lane * 4;
      if (c < rowEnd) {
        ushort4 u = *(const ushort4*)(p + c);
        v[ps * 4 + 0] = bf2f(u.x); v[ps * 4 + 1] = bf2f(u.y);
        v[ps * 4 + 2] = bf2f(u.z); v[ps * 4 + 3] = bf2f(u.w);
      } else {
        v[ps * 4 + 0] = v[ps * 4 + 1] = v[ps * 4 + 2] = v[ps * 4 + 3] = -1e30f;
      }
      m = fmaxf(m, fmaxf(fmaxf(v[ps * 4], v[ps * 4 + 1]),
                         fmaxf(v[ps * 4 + 2], v[ps * 4 + 3])));
    }
#pragma unroll
    for (int o = 32; o; o >>= 1) m = fmaxf(m, __shfl_xor(m, o));
    float ssum = 0.f;
#pragma unroll
    for (int e = 0; e < 16; ++e) { v[e] = expf(v[e] - m); ssum += v[e]; }
#pragma unroll
    for (int o = 32; o; o >>= 1) ssum += __shfl_xor(ssum, o);
    float inv = 1.f / ssum;
#pragma unroll
    for (int ps = 0; ps < 4; ++ps) {
      int c = ps * 256 + lane * 4;
      if (c < rowEnd) {
        ushort4 w4;
        w4.x = f2bf(v[ps * 4 + 0] * inv); w4.y = f2bf(v[ps * 4 + 1] * inv);
        w4.z = f2bf(v[ps * 4 + 2] * inv); w4.w = f2bf(v[ps * 4 + 3] * inv);
        *(ushort4*)(p + c) = w4;
      }
    }
  }
  __syncthreads();

  f32x4 ao = {};
  for (int kt = 0; kt < nkt; ++kt) {
    const unsigned short* Vp = VT + ((size_t)h << 16) + kt * 64;
#pragma unroll
    for (int hh = 0; hh < 2; ++hh)
      *(ushort8*)&KV[hh * 32 + srow][scol] =
          *(const ushort8*)(Vp + (size_t)(hh * 32 + srow) * 1024 + scol);
    __syncthreads();
#pragma unroll
    for (int k0 = 0; k0 < 2; ++k0) {
      bf16x8 pa = *(const bf16x8*)&S[l16][kt * 64 + k0 * 32 + quad * 8];
      bf16x8 bb = *(const bf16x8*)&KV[wave * 16 + l16][k0 * 32 + quad * 8];
      ao = __builtin_amdgcn_mfma_f32_16x16x32_bf16(pa, bb, ao, 0, 0, 0);
    }
    __syncthreads();
  }
#pragma unroll
  for (int r = 0; r < 4; ++r) {
    int rowg = qt * 16 + quad * 4 + r;
    int colg = h * 64 + wave * 16 + l16;
    af[(size_t)rowg * 1280 + colg] = f2bf(ao[r]);
  }
}

// ---------------------------------------------------------------------------
// Logits GEMM: out[1024x16384] = zn @ bheadT^T where !exited. XCD swizzle.
// ---------------------------------------------------------------------------
struct LogArgs {
  const unsigned short* A; const unsigned short* B; float* C; const int* exited;
};

__global__ __launch_bounds__(256) void logits_gemm(LogArgs g) {
  int bx = blockIdx.x, by = blockIdx.y;
  {
    int lin = bx + gridDim.x * by;
    int cpx = (gridDim.x * gridDim.y) >> 3;
    int s2 = (lin & 7) * cpx + (lin >> 3);  // bijective: 4096 % 8 == 0
    bx = s2 % gridDim.x; by = s2 / gridDim.x;
  }
  const int bm = bx * 64, bn = by * 64;
  __shared__ __align__(16) unsigned short As[64][40];
  __shared__ __align__(16) unsigned short Bs[64][40];
  const int tid = threadIdx.x;
  f32x4 acc[2][2] = {};
  gemm64(g.A + (size_t)bm * 256, 256, g.B + (size_t)bn * 256, 256, 256,
         As, Bs, tid, acc);
  const int lane = tid & 63, wave = tid >> 6;
  const int quad = lane >> 4, l16 = lane & 15;
  const int wr = (wave >> 1) * 32, wc = (wave & 1) * 32;
#pragma unroll
  for (int i = 0; i < 2; ++i)
#pragma unroll
    for (int j = 0; j < 2; ++j)
#pragma unroll
      for (int r = 0; r < 4; ++r) {
        int row = bm + wr + i * 16 + quad * 4 + r;
        int col = bn + wc + j * 16 + l16;
        if (!g.exited[row])
          g.C[(size_t)row * 16384 + col] = acc[i][j][r];
      }
}

// ---------------------------------------------------------------------------
// Small kernels
// ---------------------------------------------------------------------------
__global__ void embed_kernel(const float* wte, const float* wpe, const int* idx,
                             float* z_prev, float* z_s0, int* exited,
                             const int* i64f, float* nsq, int* counter) {
  int tok = blockIdx.x, d = threadIdx.x;
  int id = (*i64f) ? idx[2 * tok] : idx[tok];
  float v = wte[(size_t)id * 256 + d] + wpe[(size_t)tok * 256 + d];
  z_prev[tok * 256 + d] = v;
  z_s0[tok * 256 + d] = v;
  if (d == 0) exited[tok] = 0;
  if (tok == 0) {
#pragma unroll
    for (int j = 0; j < 4; ++j) nsq[d + 256 * j] = 0.f;
    if (d == 0) *counter = 0;
  }
}

__global__ __launch_bounds__(256) void conf_kernel(const float* logits, int* exited) {
  int tok = blockIdx.x;
  if (exited[tok]) return;
  const float* p = logits + ((size_t)tok << 14);
  int t = threadIdx.x, lane = t & 63, wave = t >> 6;
  float m = -1e30f;
  const float4* p4 = (const float4*)p;
  for (int j = t; j < 4096; j += 256) {
    float4 u = p4[j];
    m = fmaxf(fmaxf(fmaxf(m, u.x), u.y), fmaxf(u.z, u.w));
  }
#pragma unroll
  for (int o = 32; o; o >>= 1) m = fmaxf(m, __shfl_xor(m, o));
  __shared__ float red[4];
  if (lane == 0) red[wave] = m;
  __syncthreads();
  m = fmaxf(fmaxf(red[0], red[1]), fmaxf(red[2], red[3]));
  float s = 0.f;
  for (int j = t; j < 16384; j += 256) s += expf(p[j] - m);
#pragma unroll
  for (int o = 32; o; o >>= 1) s += __shfl_xor(s, o);
  __syncthreads();
  if (lane == 0) red[wave] = s;
  __syncthreads();
  s = red[0] + red[1] + red[2] + red[3];
  if (t == 0 && (1.f / s) > 0.9f) exited[tok] = 1;
}

// ---------------------------------------------------------------------------
// Host launch
// ---------------------------------------------------------------------------
extern "C" void kernel_launch(void* const* d_in, const int* in_sizes, int n_in,
                              void* d_out, int out_size, void* d_ws, size_t ws_size,
                              hipStream_t stream) {
  (void)out_size;
  const float* wte   = (const float*)d_in[0];
  const float* wpe   = (const float*)d_in[1];
  const float* ln1_g = (const float*)d_in[2];
  const float* ln1_b = (const float*)d_in[3];
  const float* wqkv  = (const float*)d_in[4];
  const float* wo    = (const float*)d_in[5];
  const float* ln2_g = (const float*)d_in[6];
  const float* ln2_b = (const float*)d_in[7];
  const float* w1    = (const float*)d_in[8];
  const float* b1    = (const float*)d_in[9];
  const float* w2    = (const float*)d_in[10];
  const float* b2    = (const float*)d_in[11];
  const float* eln_g = (const float*)d_in[12];
  const float* eln_b = (const float*)d_in[13];
  const float* ehead = (const float*)d_in[14];
  const int* idx = (const int*)d_in[15];
  float* out = (float*)d_out;

  float sentinel = 0.f;
  if (!(n_in == 16 && in_sizes[0] == 4194304 && in_sizes[14] == 16777216 &&
        in_sizes[15] == 1024))
    sentinel += 1000.f;
  if (ws_size < (size_t)20000000) sentinel += 2000.f;

  char* w = (char*)d_ws;
  auto alloc = [&](size_t bytes) {
    char* p = w; w += (bytes + 255) & ~(size_t)255; return p;
  };
  int* i64f        = (int*)alloc(256);
  Scalars* scarr   = (Scalars*)alloc(2 * sizeof(Scalars));  // layer-parity slots
  int* counter     = (int*)alloc(256);
  int* exited      = (int*)alloc(1024 * 4);
  float* nsq       = (float*)alloc(1024 * 4);
  float* biasf     = (float*)alloc(1792 * 4);
  float* z_prev    = (float*)alloc(1024 * 256 * 4);
  float* z_s0      = (float*)alloc(1024 * 256 * 4);
  float* z_s1      = (float*)alloc(1024 * 256 * 4);
  float* dz        = (float*)alloc(1024 * 256 * 4);
  unsigned short* zn   = (unsigned short*)alloc(1024 * 256 * 2);
  unsigned short* qkvb = (unsigned short*)alloc((size_t)1024 * 768 * 2);
  unsigned short* af   = (unsigned short*)alloc((size_t)1024 * 1280 * 2);  // [O|hmid]
  unsigned short* Sbuf = (unsigned short*)alloc((size_t)4 * 1024 * 1024 * 2);  // bheadT
  unsigned short* bcat = (unsigned short*)alloc((size_t)1792 * 256 * 2);
  unsigned short* wcat = (unsigned short*)alloc((size_t)256 * 1280 * 2);
  unsigned short* VT   = (unsigned short*)alloc((size_t)4 * 64 * 1024 * 2);

  detect_idx_kernel<<<1, 256, 0, stream>>>(idx, i64f);
  embed_kernel<<<1024, 256, 0, stream>>>(wte, wpe, idx, z_prev, z_s0, exited,
                                         i64f, nsq, counter);

  for (int i = 0; i < 4; ++i) {
    Scalars* scCur = scarr + (i & 1);
    Scalars* scPrv = (i >= 1) ? scarr + ((i - 1) & 1) : nullptr;
    // Weight prep for layer i; blocks 199+ run combine of layer i-1.
    tr_weights_kernel<<<(i == 0 ? 199 : 455), 256, 0, stream>>>(
        wqkv + (size_t)i * 196608, wo + (size_t)i * 65536,
        w1 + (size_t)i * 262144, w2 + (size_t)i * 262144,
        ln1_g + i * 256, ln1_b + i * 256, ln2_g + i * 256, ln2_b + i * 256,
        b1 + i * 1024, bcat, wcat, biasf, scCur,
        scPrv, z_prev, z_s0, z_s1, dz, exited,
        eln_g, eln_b, (i - 1) * 256, zn, (i - 1) >= 1 ? 1 : 0);
    if (i >= 2) {  // logits for layer i-1 (combine(i-1) just ran; layer-0 dead)
      tr_mat_kernel<<<dim3(256, 4), 256, 0, stream>>>(
          ehead + (size_t)(i - 1) * 4194304, Sbuf);
      LogArgs la{}; la.A = zn; la.B = Sbuf; la.C = out; la.exited = exited;
      logits_gemm<<<dim3(16, 256), 256, 0, stream>>>(la);
      conf_kernel<<<1024, 256, 0, stream>>>(out, exited);  // i-1 in {1,2}
    }
    for (int s = 0; s < 4; ++s) {
      gemm_fused1<<<dim3(16, 28), 256, 0, stream>>>(
          z_s0, z_s1, dz, bcat, biasf, qkvb, VT, af, scCur);
      attn_kernel<<<dim3(64, 4), 256, 0, stream>>>(qkvb, VT, af, &scCur->active);
      gemm_add2<<<dim3(16, 4), 256, 0, stream>>>(
          af, wcat, dz, b2 + i * 256, nsq, counter, scCur);
    }
  }
  // layer 3: standalone combine + logits (conf(3) dead)
  combine_kernel<<<256, 256, 0, stream>>>(z_prev, z_s0, z_s1, dz, exited,
                                          scarr + 1, eln_g, eln_b, 768, zn, 1);
  tr_mat_kernel<<<dim3(256, 4), 256, 0, stream>>>(ehead + (size_t)3 * 4194304, Sbuf);
  {
    LogArgs la{}; la.A = zn; la.B = Sbuf; la.C = out; la.exited = exited;
    logits_gemm<<<dim3(16, 256), 256, 0, stream>>>(la);
  }

  sentinel_kernel<<<1, 1, 0, stream>>>(out, sentinel);
}